// Round 8
// baseline (14300.227 us; speedup 1.0000x reference)
//
#include <hip/hip_runtime.h>
#include <cstdint>
#include <cstddef>

#define TT    8192
#define DIMC  256
#define DIN   1024
#define NH    8
#define HD    128
#define DST   128
#define CDIM  1280
#define DPROJ 2312
#define QP    132   // padded LDS row (floats)

__device__ __forceinline__ void seq_bounds(int t, const int* pts, int nseq,
                                           int& sq, int& lo, int& hi) {
  int acc = 0;
  for (int i = 0; i < nseq; ++i) {
    int p = pts[i];
    if (t < acc + p) { sq = i; lo = acc; hi = acc + p; return; }
    acc += p;
  }
  sq = nseq; lo = acc; hi = acc + 1;
}

__device__ __forceinline__ float siluf(float v) {
  return v / (1.f + __expf(-v));
}

// ---- LayerNorm; writes forward rows u2[0:T) and reversed rows u2[T:2T) ----
__global__ __launch_bounds__(256) void ln_kernel(
    const float* __restrict__ x, const int* __restrict__ pts, int nseq,
    const float* __restrict__ lnw, const float* __restrict__ lnb,
    float* __restrict__ u2, float* __restrict__ resp) {
  int t = blockIdx.x, tid = threadIdx.x;
  float v = x[(size_t)t * DIMC + tid];
  float s1 = v, s2 = v * v;
#pragma unroll
  for (int off = 32; off; off >>= 1) {
    s1 += __shfl_down(s1, off);
    s2 += __shfl_down(s2, off);
  }
  __shared__ float r1[4], r2[4];
  if ((tid & 63) == 0) { r1[tid >> 6] = s1; r2[tid >> 6] = s2; }
  __syncthreads();
  float tot1 = r1[0] + r1[1] + r1[2] + r1[3];
  float tot2 = r2[0] + r2[1] + r2[2] + r2[3];
  float mu  = tot1 * (1.f / 256.f);
  float var = tot2 * (1.f / 256.f) - mu * mu;
  float rs  = rsqrtf(var + 1e-5f);
  float xn  = (v - mu) * rs * lnw[tid] + lnb[tid];
  u2[(size_t)t * DIMC + tid] = xn;
  int sq, lo, hi; seq_bounds(t, pts, nseq, sq, lo, hi);
  int rt = lo + hi - 1 - t;
  u2[(size_t)(TT + rt) * DIMC + tid] = xn;   // u2_rev[rt] = xn[t]  <=>  xn[rev]
  resp[(size_t)t * DIMC + tid] = v;
}

// ---------------- generic fp32 GEMM:  C[M,N] = A[M,K] @ B[N,K]^T (+bias) --
__global__ __launch_bounds__(256) void gemm_nt(
    const float* __restrict__ A, const float* __restrict__ B,
    float* __restrict__ C, int M, int N, int K, const float* __restrict__ bias) {
  __shared__ float As[16][QP];
  __shared__ float Bs[16][QP];
  int tid = threadIdx.x;
  int tx = tid & 15, ty = tid >> 4;
  int m0 = blockIdx.y * 128, n0 = blockIdx.x * 128;
  int lr = tid >> 1, lk = (tid & 1) * 8;
  float acc[8][8] = {};
  for (int k0 = 0; k0 < K; k0 += 16) {
    float4 av0 = {0,0,0,0}, av1 = {0,0,0,0}, bv0 = {0,0,0,0}, bv1 = {0,0,0,0};
    if (m0 + lr < M) {
      const float* ap = A + (size_t)(m0 + lr) * K + k0 + lk;
      av0 = *(const float4*)ap; av1 = *(const float4*)(ap + 4);
    }
    if (n0 + lr < N) {
      const float* bp = B + (size_t)(n0 + lr) * K + k0 + lk;
      bv0 = *(const float4*)bp; bv1 = *(const float4*)(bp + 4);
    }
    As[lk+0][lr]=av0.x; As[lk+1][lr]=av0.y; As[lk+2][lr]=av0.z; As[lk+3][lr]=av0.w;
    As[lk+4][lr]=av1.x; As[lk+5][lr]=av1.y; As[lk+6][lr]=av1.z; As[lk+7][lr]=av1.w;
    Bs[lk+0][lr]=bv0.x; Bs[lk+1][lr]=bv0.y; Bs[lk+2][lr]=bv0.z; Bs[lk+3][lr]=bv0.w;
    Bs[lk+4][lr]=bv1.x; Bs[lk+5][lr]=bv1.y; Bs[lk+6][lr]=bv1.z; Bs[lk+7][lr]=bv1.w;
    __syncthreads();
#pragma unroll
    for (int kk = 0; kk < 16; ++kk) {
      float a[8], b[8];
      *(float4*)&a[0] = *(const float4*)&As[kk][ty*8];
      *(float4*)&a[4] = *(const float4*)&As[kk][ty*8+4];
      *(float4*)&b[0] = *(const float4*)&Bs[kk][tx*8];
      *(float4*)&b[4] = *(const float4*)&Bs[kk][tx*8+4];
#pragma unroll
      for (int i = 0; i < 8; ++i)
#pragma unroll
        for (int j = 0; j < 8; ++j)
          acc[i][j] += a[i] * b[j];
    }
    __syncthreads();
  }
#pragma unroll
  for (int i = 0; i < 8; ++i) {
    int m = m0 + ty*8 + i;
    if (m >= M) continue;
#pragma unroll
    for (int j = 0; j < 8; ++j) {
      int n = n0 + tx*8 + j;
      if (n < N) C[(size_t)m * N + n] = acc[i][j] + (bias ? bias[n] : 0.f);
    }
  }
}

// ---- plain causal conv4 + SiLU + dt softplus on ONE stream's own rows ----
__global__ __launch_bounds__(256) void conv_plain(
    const float* __restrict__ zxbd, const int* __restrict__ pts, int nseq,
    const float* __restrict__ convw, const float* __restrict__ convb,
    const float* __restrict__ dtb,
    float* __restrict__ xbcd, float* __restrict__ dtpd) {
  int t = blockIdx.x;             // [0, T)
  int tid = threadIdx.x;
  int sq, lo, hi; seq_bounds(t, pts, nseq, sq, lo, hi);
  for (int c = tid; c < CDIM; c += 256) {
    float acc = convb[c];
#pragma unroll
    for (int j = 0; j < 4; ++j) {
      int sh = 3 - j;
      if (t - sh >= lo)
        acc += convw[c * 4 + j] * zxbd[(size_t)(t - sh) * DPROJ + DIN + c];
    }
    xbcd[(size_t)t * CDIM + c] = siluf(acc);
  }
  if (tid < NH) {
    float v = zxbd[(size_t)t * DPROJ + (DPROJ - NH) + tid] + dtb[tid];
    dtpd[(size_t)t * NH + tid] = (v > 20.f) ? v : log1pf(expf(v));
  }
}

// ---- sequential selective scan, one stream; block = head -----------------
// State h[p][n] in registers: thread (tx,ty): n = tx*8+jn, p = ty*8+jp.
__global__ __launch_bounds__(256) void seq_scan_d(
    const float* __restrict__ xbcd, const float* __restrict__ dtpd,
    const int* __restrict__ pts, int nseq,
    const float* __restrict__ A_log, const float* __restrict__ Dv,
    float* __restrict__ ysd) {
  int h   = blockIdx.x;           // [0, 8)
  int tid = threadIdx.x;
  int tx  = tid & 15, ty = tid >> 4;
  float A  = -expf(A_log[h]);
  float Dh = Dv[h];
  float H[8][8];
#pragma unroll
  for (int i = 0; i < 8; ++i)
#pragma unroll
    for (int j = 0; j < 8; ++j) H[i][j] = 0.f;

  int nb = 0, si = 0;
  for (int t = 0; t < TT; ++t) {
    bool rst = (t == nb);
    if (rst) { nb += pts[si]; ++si; }
    const float* row = xbcd + (size_t)t * CDIM;
    float dt = dtpd[(size_t)t * NH + h];
    float keep = rst ? 0.f : __expf(dt * A);
    float bs[8], cs[8], xs[8];
    *(float4*)&bs[0] = *(const float4*)(row + DIN + tx*8);
    *(float4*)&bs[4] = *(const float4*)(row + DIN + tx*8 + 4);
    *(float4*)&cs[0] = *(const float4*)(row + DIN + DST + tx*8);
    *(float4*)&cs[4] = *(const float4*)(row + DIN + DST + tx*8 + 4);
    *(float4*)&xs[0] = *(const float4*)(row + h*HD + ty*8);
    *(float4*)&xs[4] = *(const float4*)(row + h*HD + ty*8 + 4);
    float part[8];
#pragma unroll
    for (int jp = 0; jp < 8; ++jp) {
      float coef = dt * xs[jp];
      float acc = 0.f;
#pragma unroll
      for (int jn = 0; jn < 8; ++jn) {
        float hv = keep * H[jp][jn] + coef * bs[jn];
        H[jp][jn] = hv;
        acc += hv * cs[jn];
      }
      part[jp] = acc;
    }
#pragma unroll
    for (int off = 1; off < 16; off <<= 1)
#pragma unroll
      for (int jp = 0; jp < 8; ++jp)
        part[jp] += __shfl_xor(part[jp], off);
    if (tx == 0) {
      float* yp = ysd + (size_t)t * DIN + h*HD + ty*8;
      *(float4*)yp = make_float4(part[0] + Dh*xs[0], part[1] + Dh*xs[1],
                                 part[2] + Dh*xs[2], part[3] + Dh*xs[3]);
      *(float4*)(yp+4) = make_float4(part[4] + Dh*xs[4], part[5] + Dh*xs[5],
                                     part[6] + Dh*xs[6], part[7] + Dh*xs[7]);
    }
  }
}

// ---- gate (silu(z)) + RMSNorm(1024) * gn_w; stream's own z rows ----------
__global__ __launch_bounds__(256) void gate_plain(
    float* __restrict__ ysd, const float* __restrict__ zxbd,
    const float* __restrict__ gnw) {
  int t = blockIdx.x, tid = threadIdx.x;
  float4 y = *(float4*)(ysd + (size_t)t * DIN + tid * 4);
  float4 z = *(const float4*)(zxbd + (size_t)t * DPROJ + tid * 4);
  y.x *= siluf(z.x); y.y *= siluf(z.y); y.z *= siluf(z.z); y.w *= siluf(z.w);
  float ss = y.x*y.x + y.y*y.y + y.z*y.z + y.w*y.w;
#pragma unroll
  for (int off = 32; off; off >>= 1) ss += __shfl_down(ss, off);
  __shared__ float red[4];
  if ((tid & 63) == 0) red[tid >> 6] = ss;
  __syncthreads();
  float tot = red[0] + red[1] + red[2] + red[3];
  float sc = rsqrtf(tot * (1.f / 1024.f) + 1e-5f);
  float4 g = *(const float4*)(gnw + tid * 4);
  y.x *= sc * g.x; y.y *= sc * g.y; y.z *= sc * g.z; y.w *= sc * g.w;
  *(float4*)(ysd + (size_t)t * DIN + tid * 4) = y;
}

// ---------------- build concat [o1[t], o2[rev(t)]] -----------------------
__global__ __launch_bounds__(256) void cat_kernel(
    const float* __restrict__ o, const int* __restrict__ pts, int nseq,
    float* __restrict__ acat) {
  int t = blockIdx.x, tid = threadIdx.x;
  int sq, lo, hi; seq_bounds(t, pts, nseq, sq, lo, hi);
  int rt = lo + hi - 1 - t;
  acat[(size_t)t * 512 + tid]       = o[(size_t)t * DIMC + tid];
  acat[(size_t)t * 512 + 256 + tid] = o[(size_t)(TT + rt) * DIMC + tid];
}

__global__ void zero_out(float* p, size_t n) {
  size_t i = (size_t)blockIdx.x * blockDim.x + threadIdx.x;
  if (i < n) p[i] = 0.f;
}

extern "C" void kernel_launch(void* const* d_in, const int* in_sizes, int n_in,
                              void* d_out, int out_size, void* d_ws, size_t ws_size,
                              hipStream_t stream) {
  const float* x      = (const float*)d_in[0];
  const int*   pts    = (const int*)  d_in[1];
  const float* lnw    = (const float*)d_in[2];
  const float* lnb    = (const float*)d_in[3];
  const float* W_in   = (const float*)d_in[4];
  const float* convw  = (const float*)d_in[5];
  const float* convb  = (const float*)d_in[6];
  const float* dtb    = (const float*)d_in[7];
  const float* A_log  = (const float*)d_in[8];
  const float* Dv     = (const float*)d_in[9];
  const float* gnw    = (const float*)d_in[10];
  const float* W_out  = (const float*)d_in[11];
  const float* W_proj = (const float*)d_in[12];
  const float* b_proj = (const float*)d_in[13];
  int nseq = in_sizes[1];

  // ---- workspace (floats). Per-dir scratch (zxbd/xbcd/ysd/dtpd) reused. --
  const size_t U2   = (size_t)2 * TT * DIMC;    //  4,194,304
  const size_t OBUF = (size_t)2 * TT * DIMC;    //  4,194,304
  const size_t ACAT = (size_t)TT * 2 * DIMC;    //  4,194,304
  const size_t ZXBD = (size_t)TT * DPROJ;       // 18,939,904
  const size_t XBCD = (size_t)TT * CDIM;        // 10,485,760
  const size_t YSD  = (size_t)TT * DIN;         //  8,388,608
  const size_t DTPD = (size_t)TT * NH;          //     65,536
  const size_t NEED = (U2 + OBUF + ACAT + ZXBD + XBCD + YSD + DTPD) * sizeof(float);

  if (ws_size < NEED) {
    size_t n = (size_t)out_size;
    zero_out<<<(unsigned)((n + 255) / 256), 256, 0, stream>>>((float*)d_out, n);
    return;
  }

  float* ws   = (float*)d_ws;
  float* u2   = ws;
  float* o    = u2 + U2;
  float* acat = o + OBUF;
  float* zxbd = acat + ACAT;
  float* xbcd = zxbd + ZXBD;
  float* ysd  = xbcd + XBCD;
  float* dtpd = ysd + YSD;

  float* outp = (float*)d_out;
  float* resp = outp + (size_t)TT * DIMC;

  ln_kernel<<<TT, 256, 0, stream>>>(x, pts, nseq, lnw, lnb, u2, resp);

  for (int d = 0; d < 2; ++d) {
    const float* ud = u2 + (size_t)d * TT * DIMC;
    float*       od = o  + (size_t)d * TT * DIMC;
    gemm_nt<<<dim3((DPROJ + 127) / 128, TT / 128), 256, 0, stream>>>(
        ud, W_in, zxbd, TT, DPROJ, DIMC, nullptr);
    conv_plain<<<TT, 256, 0, stream>>>(zxbd, pts, nseq, convw, convb, dtb,
                                       xbcd, dtpd);
    seq_scan_d<<<NH, 256, 0, stream>>>(xbcd, dtpd, pts, nseq, A_log, Dv, ysd);
    gate_plain<<<TT, 256, 0, stream>>>(ysd, zxbd, gnw);
    gemm_nt<<<dim3(DIMC / 128, TT / 128), 256, 0, stream>>>(
        ysd, W_out, od, TT, DIMC, DIN, nullptr);
  }

  cat_kernel<<<TT, 256, 0, stream>>>(o, pts, nseq, acat);
  gemm_nt<<<dim3(DIMC / 128, TT / 128), 256, 0, stream>>>(
      acat, W_proj, outp, TT, DIMC, 2 * DIMC, b_proj);
}

// Round 10
// 1415.457 us; speedup vs baseline: 10.1029x; 10.1029x over previous
//
#include <hip/hip_runtime.h>
#include <cstdint>
#include <cstddef>

#define TT    8192
#define DIMC  256
#define DIN   1024
#define NH    8
#define HD    128
#define DST   128
#define CDIM  1280
#define DPROJ 2312
#define NCH   64
#define QP    132   // padded LDS row (floats)

__device__ __forceinline__ void seq_bounds(int t, const int* pts, int nseq,
                                           int& sq, int& lo, int& hi) {
  int acc = 0;
  for (int i = 0; i < nseq; ++i) {
    int p = pts[i];
    if (t < acc + p) { sq = i; lo = acc; hi = acc + p; return; }
    acc += p;
  }
  sq = nseq; lo = acc; hi = acc + 1;
}

__device__ __forceinline__ float siluf(float v) {
  return v / (1.f + __expf(-v));
}

// ---- LayerNorm; writes forward rows u2[0:T) and reversed rows u2[T:2T) ----
__global__ __launch_bounds__(256) void ln_kernel(
    const float* __restrict__ x, const int* __restrict__ pts, int nseq,
    const float* __restrict__ lnw, const float* __restrict__ lnb,
    float* __restrict__ u2, float* __restrict__ resp) {
  int t = blockIdx.x, tid = threadIdx.x;
  float v = x[(size_t)t * DIMC + tid];
  float s1 = v, s2 = v * v;
#pragma unroll
  for (int off = 32; off; off >>= 1) {
    s1 += __shfl_down(s1, off);
    s2 += __shfl_down(s2, off);
  }
  __shared__ float r1[4], r2[4];
  if ((tid & 63) == 0) { r1[tid >> 6] = s1; r2[tid >> 6] = s2; }
  __syncthreads();
  float tot1 = r1[0] + r1[1] + r1[2] + r1[3];
  float tot2 = r2[0] + r2[1] + r2[2] + r2[3];
  float mu  = tot1 * (1.f / 256.f);
  float var = tot2 * (1.f / 256.f) - mu * mu;
  float rs  = rsqrtf(var + 1e-5f);
  float xn  = (v - mu) * rs * lnw[tid] + lnb[tid];
  u2[(size_t)t * DIMC + tid] = xn;
  int sq, lo, hi; seq_bounds(t, pts, nseq, sq, lo, hi);
  int rt = lo + hi - 1 - t;
  u2[(size_t)(TT + rt) * DIMC + tid] = xn;
  resp[(size_t)t * DIMC + tid] = v;
}

// ---------------- generic fp32 GEMM:  C[M,N] = A[M,K] @ B[N,K]^T (+bias) --
__global__ __launch_bounds__(256) void gemm_nt(
    const float* __restrict__ A, const float* __restrict__ B,
    float* __restrict__ C, int M, int N, int K, const float* __restrict__ bias) {
  __shared__ float As[16][QP];
  __shared__ float Bs[16][QP];
  int tid = threadIdx.x;
  int tx = tid & 15, ty = tid >> 4;
  int m0 = blockIdx.y * 128, n0 = blockIdx.x * 128;
  int lr = tid >> 1, lk = (tid & 1) * 8;
  float acc[8][8] = {};
  for (int k0 = 0; k0 < K; k0 += 16) {
    float4 av0 = {0,0,0,0}, av1 = {0,0,0,0}, bv0 = {0,0,0,0}, bv1 = {0,0,0,0};
    if (m0 + lr < M) {
      const float* ap = A + (size_t)(m0 + lr) * K + k0 + lk;
      av0 = *(const float4*)ap; av1 = *(const float4*)(ap + 4);
    }
    if (n0 + lr < N) {
      const float* bp = B + (size_t)(n0 + lr) * K + k0 + lk;
      bv0 = *(const float4*)bp; bv1 = *(const float4*)(bp + 4);
    }
    As[lk+0][lr]=av0.x; As[lk+1][lr]=av0.y; As[lk+2][lr]=av0.z; As[lk+3][lr]=av0.w;
    As[lk+4][lr]=av1.x; As[lk+5][lr]=av1.y; As[lk+6][lr]=av1.z; As[lk+7][lr]=av1.w;
    Bs[lk+0][lr]=bv0.x; Bs[lk+1][lr]=bv0.y; Bs[lk+2][lr]=bv0.z; Bs[lk+3][lr]=bv0.w;
    Bs[lk+4][lr]=bv1.x; Bs[lk+5][lr]=bv1.y; Bs[lk+6][lr]=bv1.z; Bs[lk+7][lr]=bv1.w;
    __syncthreads();
#pragma unroll
    for (int kk = 0; kk < 16; ++kk) {
      float a[8], b[8];
      *(float4*)&a[0] = *(const float4*)&As[kk][ty*8];
      *(float4*)&a[4] = *(const float4*)&As[kk][ty*8+4];
      *(float4*)&b[0] = *(const float4*)&Bs[kk][tx*8];
      *(float4*)&b[4] = *(const float4*)&Bs[kk][tx*8+4];
#pragma unroll
      for (int i = 0; i < 8; ++i)
#pragma unroll
        for (int j = 0; j < 8; ++j)
          acc[i][j] += a[i] * b[j];
    }
    __syncthreads();
  }
#pragma unroll
  for (int i = 0; i < 8; ++i) {
    int m = m0 + ty*8 + i;
    if (m >= M) continue;
#pragma unroll
    for (int j = 0; j < 8; ++j) {
      int n = n0 + tx*8 + j;
      if (n < N) C[(size_t)m * N + n] = acc[i][j] + (bias ? bias[n] : 0.f);
    }
  }
}

// ---- plain causal conv4 + SiLU + dt softplus on ONE stream's own rows ----
__global__ __launch_bounds__(256) void conv_plain(
    const float* __restrict__ zxbd, const int* __restrict__ pts, int nseq,
    const float* __restrict__ convw, const float* __restrict__ convb,
    const float* __restrict__ dtb,
    float* __restrict__ xbcd, float* __restrict__ dtpd) {
  int t = blockIdx.x;             // [0, T)
  int tid = threadIdx.x;
  int sq, lo, hi; seq_bounds(t, pts, nseq, sq, lo, hi);
  for (int c = tid; c < CDIM; c += 256) {
    float acc = convb[c];
#pragma unroll
    for (int j = 0; j < 4; ++j) {
      int sh = 3 - j;
      if (t - sh >= lo)
        acc += convw[c * 4 + j] * zxbd[(size_t)(t - sh) * DPROJ + DIN + c];
    }
    xbcd[(size_t)t * CDIM + c] = siluf(acc);
  }
  if (tid < NH) {
    float v = zxbd[(size_t)t * DPROJ + (DPROJ - NH) + tid] + dtb[tid];
    dtpd[(size_t)t * NH + tid] = (v > 20.f) ? v : log1pf(expf(v));
  }
}

// ---- intra-chunk SSD (one stream): Y_intra + D*x, chunk state S_c --------
__global__ __launch_bounds__(256) void intra_d(
    const float* __restrict__ xbcd, const float* __restrict__ dtpd,
    const int* __restrict__ pts, int nseq,
    const float* __restrict__ A_log, const float* __restrict__ Dv,
    float* __restrict__ ysd, float* __restrict__ states, float* __restrict__ alpha) {
  __shared__ float B1[128 * QP];
  __shared__ float B2[128 * QP];
  __shared__ float cd[128];
  __shared__ float dts[128];
  __shared__ int   sqv[128];
  int b  = blockIdx.x;            // [0, NH*NCH)
  int h  = b & 7;
  int c  = b >> 3;
  int rb = c * 128;
  int tid = threadIdx.x;
  int tx = tid & 15, ty = tid >> 4;
  float A = -expf(A_log[h]);

  if (tid < 128) {
    float d = dtpd[(size_t)(rb + tid) * NH + h];
    dts[tid] = d;
    cd[tid]  = d;
    int s, lo, hi; seq_bounds(rb + tid, pts, nseq, s, lo, hi);
    sqv[tid] = s;
  }
  __syncthreads();
  for (int off = 1; off < 128; off <<= 1) {     // inclusive prefix sum of dt
    float add = (tid < 128 && tid >= off) ? cd[tid - off] : 0.f;
    __syncthreads();
    if (tid < 128) cd[tid] += add;
    __syncthreads();
  }
  for (int it = 0; it < 16; ++it) {             // C^T -> B1[n][t], B^T -> B2[n][s]
    int l = it * 1024 + tid * 4;
    int i = l >> 7, n = l & 127;
    const float* base = xbcd + (size_t)(rb + i) * CDIM + DIN;
    float4 cv = *(const float4*)(base + DST + n);
    float4 bv = *(const float4*)(base + n);
    B1[(n+0)*QP+i]=cv.x; B1[(n+1)*QP+i]=cv.y; B1[(n+2)*QP+i]=cv.z; B1[(n+3)*QP+i]=cv.w;
    B2[(n+0)*QP+i]=bv.x; B2[(n+1)*QP+i]=bv.y; B2[(n+2)*QP+i]=bv.z; B2[(n+3)*QP+i]=bv.w;
  }
  __syncthreads();
  float g[8][8] = {};                           // G[t][s] = sum_n C[t][n] B[s][n]
  for (int n = 0; n < 128; ++n) {
    float a[8], bb[8];
    *(float4*)&a[0]  = *(const float4*)&B1[n*QP + ty*8];
    *(float4*)&a[4]  = *(const float4*)&B1[n*QP + ty*8 + 4];
    *(float4*)&bb[0] = *(const float4*)&B2[n*QP + tx*8];
    *(float4*)&bb[4] = *(const float4*)&B2[n*QP + tx*8 + 4];
#pragma unroll
    for (int i = 0; i < 8; ++i)
#pragma unroll
      for (int j = 0; j < 8; ++j)
        g[i][j] += a[i] * bb[j];
  }
  __syncthreads();
#pragma unroll
  for (int i = 0; i < 8; ++i) {                 // masked decayed M -> B1[s][t]
    int t = ty*8 + i;
    float cdt = cd[t]; int st_ = sqv[t];
#pragma unroll
    for (int j = 0; j < 8; ++j) {
      int s = tx*8 + j;
      float m = 0.f;
      if (s <= t && sqv[s] == st_) m = g[i][j] * __expf(A * (cdt - cd[s])) * dts[s];
      B1[s*QP + t] = m;
    }
  }
  for (int it = 0; it < 16; ++it) {             // X -> B2[s][p]
    int l = it * 1024 + tid * 4;
    int i = l >> 7, p = l & 127;
    float4 xv = *(const float4*)(xbcd + (size_t)(rb + i) * CDIM + h * HD + p);
    *(float4*)&B2[i*QP + p] = xv;
  }
  __syncthreads();
  float y[8][8] = {};                           // Y[t][p] = sum_s M[t][s] X[s][p]
  for (int s = 0; s < 128; ++s) {
    float a[8], xx[8];
    *(float4*)&a[0]  = *(const float4*)&B1[s*QP + ty*8];
    *(float4*)&a[4]  = *(const float4*)&B1[s*QP + ty*8 + 4];
    *(float4*)&xx[0] = *(const float4*)&B2[s*QP + tx*8];
    *(float4*)&xx[4] = *(const float4*)&B2[s*QP + tx*8 + 4];
#pragma unroll
    for (int i = 0; i < 8; ++i)
#pragma unroll
      for (int j = 0; j < 8; ++j)
        y[i][j] += a[i] * xx[j];
  }
  float Dh = Dv[h];
#pragma unroll
  for (int i = 0; i < 8; ++i) {
    int t = ty*8 + i;
    float out[8];
#pragma unroll
    for (int j = 0; j < 8; ++j) out[j] = y[i][j] + Dh * B2[t*QP + tx*8 + j];
    float* yp = ysd + (size_t)(rb + t) * DIN + h * HD + tx*8;
    *(float4*)yp       = make_float4(out[0], out[1], out[2], out[3]);
    *(float4*)(yp + 4) = make_float4(out[4], out[5], out[6], out[7]);
  }
  __syncthreads();
  float cdend = cd[127];
  int sqend = sqv[127];
  for (int it = 0; it < 16; ++it) {             // weighted B -> B1[s][n]
    int l = it * 1024 + tid * 4;
    int i = l >> 7, n = l & 127;
    float w = (sqv[i] == sqend) ? __expf(A * (cdend - cd[i])) * dts[i] : 0.f;
    float4 bv = *(const float4*)(xbcd + (size_t)(rb + i) * CDIM + DIN + n);
    bv.x *= w; bv.y *= w; bv.z *= w; bv.w *= w;
    *(float4*)&B1[i*QP + n] = bv;
  }
  __syncthreads();
  float st[8][8] = {};                          // S[n][p] = sum_s w_s B[s][n] X[s][p]
  for (int s = 0; s < 128; ++s) {
    float bn[8], xx[8];
    *(float4*)&bn[0] = *(const float4*)&B1[s*QP + ty*8];
    *(float4*)&bn[4] = *(const float4*)&B1[s*QP + ty*8 + 4];
    *(float4*)&xx[0] = *(const float4*)&B2[s*QP + tx*8];
    *(float4*)&xx[4] = *(const float4*)&B2[s*QP + tx*8 + 4];
#pragma unroll
    for (int i = 0; i < 8; ++i)
#pragma unroll
      for (int j = 0; j < 8; ++j)
        st[i][j] += bn[i] * xx[j];
  }
  float* sp = states + ((size_t)h * NCH + c) * 16384;
#pragma unroll
  for (int i = 0; i < 8; ++i) {
    int n = ty*8 + i;
    *(float4*)(sp + n*128 + tx*8)     = make_float4(st[i][0], st[i][1], st[i][2], st[i][3]);
    *(float4*)(sp + n*128 + tx*8 + 4) = make_float4(st[i][4], st[i][5], st[i][6], st[i][7]);
  }
  if (tid == 0)
    alpha[h * NCH + c] = (sqv[0] == sqend) ? __expf(A * cdend) : 0.f;
}

// ---- sequential inter-chunk state pass (one stream); block = head --------
__global__ __launch_bounds__(256) void state_pass_d(
    float* __restrict__ states, const float* __restrict__ alpha,
    const int* __restrict__ pts, int nseq) {
  int hb = blockIdx.x;           // head
  int tid = threadIdx.x;
  float4 h[16];
#pragma unroll
  for (int i = 0; i < 16; ++i) h[i] = make_float4(0.f, 0.f, 0.f, 0.f);
  for (int c = 0; c < NCH; ++c) {
    int tg = c * 128;
    bool bnd = (tg == 0);
    int acc = 0;
    for (int i = 0; i < nseq; ++i) { acc += pts[i]; if (acc == tg) bnd = true; }
    if (bnd) {
#pragma unroll
      for (int i = 0; i < 16; ++i) h[i] = make_float4(0.f, 0.f, 0.f, 0.f);
    }
    float al = alpha[hb * NCH + c];
    float* sp = states + ((size_t)hb * NCH + c) * 16384;
#pragma unroll
    for (int i = 0; i < 16; ++i) {
      float* p = sp + i * 1024 + tid * 4;
      float4 s = *(float4*)p;
      *(float4*)p = h[i];                     // store h_in(c)
      h[i].x = al * h[i].x + s.x;
      h[i].y = al * h[i].y + s.y;
      h[i].z = al * h[i].z + s.z;
      h[i].w = al * h[i].w + s.w;
    }
  }
}

// ---- inter-chunk output (one stream):  ys += gamma_t * (C_t . h_in) ------
__global__ __launch_bounds__(256) void inter_d(
    const float* __restrict__ xbcd, const float* __restrict__ dtpd,
    const int* __restrict__ pts, int nseq,
    const float* __restrict__ A_log,
    const float* __restrict__ states, float* __restrict__ ysd) {
  __shared__ float B1[128 * QP];   // C^T: B1[n][t]
  __shared__ float B2[128 * QP];   // h_in: B2[n][p]
  __shared__ float cd[128];
  __shared__ int   sqv[128];
  int b  = blockIdx.x;
  int h  = b & 7;
  int c  = b >> 3;
  int rb = c * 128;
  int tid = threadIdx.x;
  int tx = tid & 15, ty = tid >> 4;
  float A = -expf(A_log[h]);

  if (tid < 128) {
    cd[tid] = dtpd[(size_t)(rb + tid) * NH + h];
    int s, lo, hi; seq_bounds(rb + tid, pts, nseq, s, lo, hi);
    sqv[tid] = s;
  }
  __syncthreads();
  for (int off = 1; off < 128; off <<= 1) {
    float add = (tid < 128 && tid >= off) ? cd[tid - off] : 0.f;
    __syncthreads();
    if (tid < 128) cd[tid] += add;
    __syncthreads();
  }
  const float* sp = states + ((size_t)h * NCH + c) * 16384;
  for (int it = 0; it < 16; ++it) {
    int l = it * 1024 + tid * 4;
    int r = l >> 7, q = l & 127;   // for C: r=t,q=n.  for states: r=n,q=p.
    float4 cv = *(const float4*)(xbcd + (size_t)(rb + r) * CDIM + DIN + DST + q);
    B1[(q+0)*QP+r]=cv.x; B1[(q+1)*QP+r]=cv.y; B1[(q+2)*QP+r]=cv.z; B1[(q+3)*QP+r]=cv.w;
    float4 hv = *(const float4*)(sp + l);
    *(float4*)&B2[r*QP + q] = hv;
  }
  __syncthreads();
  float y[8][8] = {};
  for (int n = 0; n < 128; ++n) {
    float a[8], hh[8];
    *(float4*)&a[0]  = *(const float4*)&B1[n*QP + ty*8];
    *(float4*)&a[4]  = *(const float4*)&B1[n*QP + ty*8 + 4];
    *(float4*)&hh[0] = *(const float4*)&B2[n*QP + tx*8];
    *(float4*)&hh[4] = *(const float4*)&B2[n*QP + tx*8 + 4];
#pragma unroll
    for (int i = 0; i < 8; ++i)
#pragma unroll
      for (int j = 0; j < 8; ++j)
        y[i][j] += a[i] * hh[j];
  }
#pragma unroll
  for (int i = 0; i < 8; ++i) {
    int t = ty*8 + i;
    float gam = (sqv[t] == sqv[0]) ? __expf(A * cd[t]) : 0.f;
    float* yp = ysd + (size_t)(rb + t) * DIN + h * HD + tx*8;
    float4 v0 = *(float4*)yp;
    float4 v1 = *(float4*)(yp + 4);
    v0.x += gam * y[i][0]; v0.y += gam * y[i][1];
    v0.z += gam * y[i][2]; v0.w += gam * y[i][3];
    v1.x += gam * y[i][4]; v1.y += gam * y[i][5];
    v1.z += gam * y[i][6]; v1.w += gam * y[i][7];
    *(float4*)yp = v0; *(float4*)(yp + 4) = v1;
  }
}

// ---- gate (silu(z)) + RMSNorm(1024) * gn_w; stream's own z rows ----------
__global__ __launch_bounds__(256) void gate_plain(
    float* __restrict__ ysd, const float* __restrict__ zxbd,
    const float* __restrict__ gnw) {
  int t = blockIdx.x, tid = threadIdx.x;
  float4 y = *(float4*)(ysd + (size_t)t * DIN + tid * 4);
  float4 z = *(const float4*)(zxbd + (size_t)t * DPROJ + tid * 4);
  y.x *= siluf(z.x); y.y *= siluf(z.y); y.z *= siluf(z.z); y.w *= siluf(z.w);
  float ss = y.x*y.x + y.y*y.y + y.z*y.z + y.w*y.w;
#pragma unroll
  for (int off = 32; off; off >>= 1) ss += __shfl_down(ss, off);
  __shared__ float red[4];
  if ((tid & 63) == 0) red[tid >> 6] = ss;
  __syncthreads();
  float tot = red[0] + red[1] + red[2] + red[3];
  float sc = rsqrtf(tot * (1.f / 1024.f) + 1e-5f);
  float4 g = *(const float4*)(gnw + tid * 4);
  y.x *= sc * g.x; y.y *= sc * g.y; y.z *= sc * g.z; y.w *= sc * g.w;
  *(float4*)(ysd + (size_t)t * DIN + tid * 4) = y;
}

// ---------------- build concat [o1[t], o2[rev(t)]] -----------------------
__global__ __launch_bounds__(256) void cat_kernel(
    const float* __restrict__ o, const int* __restrict__ pts, int nseq,
    float* __restrict__ acat) {
  int t = blockIdx.x, tid = threadIdx.x;
  int sq, lo, hi; seq_bounds(t, pts, nseq, sq, lo, hi);
  int rt = lo + hi - 1 - t;
  acat[(size_t)t * 512 + tid]       = o[(size_t)t * DIMC + tid];
  acat[(size_t)t * 512 + 256 + tid] = o[(size_t)(TT + rt) * DIMC + tid];
}

__global__ void zero_out(float* p, size_t n) {
  size_t i = (size_t)blockIdx.x * blockDim.x + threadIdx.x;
  if (i < n) p[i] = 0.f;
}

extern "C" void kernel_launch(void* const* d_in, const int* in_sizes, int n_in,
                              void* d_out, int out_size, void* d_ws, size_t ws_size,
                              hipStream_t stream) {
  const float* x      = (const float*)d_in[0];
  const int*   pts    = (const int*)  d_in[1];
  const float* lnw    = (const float*)d_in[2];
  const float* lnb    = (const float*)d_in[3];
  const float* W_in   = (const float*)d_in[4];
  const float* convw  = (const float*)d_in[5];
  const float* convb  = (const float*)d_in[6];
  const float* dtb    = (const float*)d_in[7];
  const float* A_log  = (const float*)d_in[8];
  const float* Dv     = (const float*)d_in[9];
  const float* gnw    = (const float*)d_in[10];
  const float* W_out  = (const float*)d_in[11];
  const float* W_proj = (const float*)d_in[12];
  const float* b_proj = (const float*)d_in[13];
  int nseq = in_sizes[1];

  // ---- workspace (floats). Per-dir scratch reused across the two dirs. ---
  const size_t U2    = (size_t)2 * TT * DIMC;
  const size_t OBUF  = (size_t)2 * TT * DIMC;
  const size_t ACAT  = (size_t)TT * 2 * DIMC;
  const size_t ZXBD  = (size_t)TT * DPROJ;
  const size_t XBCD  = (size_t)TT * CDIM;
  const size_t YSD   = (size_t)TT * DIN;
  const size_t DTPD  = (size_t)TT * NH;
  const size_t STATE = (size_t)NH * NCH * 16384;
  const size_t ALPHA = (size_t)NH * NCH;
  const size_t NEED  = (U2 + OBUF + ACAT + ZXBD + XBCD + YSD + DTPD +
                        STATE + ALPHA) * sizeof(float);

  if (ws_size < NEED) {
    size_t n = (size_t)out_size;
    zero_out<<<(unsigned)((n + 255) / 256), 256, 0, stream>>>((float*)d_out, n);
    return;
  }

  float* ws     = (float*)d_ws;
  float* u2     = ws;
  float* o      = u2 + U2;
  float* acat   = o + OBUF;
  float* zxbd   = acat + ACAT;
  float* xbcd   = zxbd + ZXBD;
  float* ysd    = xbcd + XBCD;
  float* dtpd   = ysd + YSD;
  float* states = dtpd + DTPD;
  float* alpha  = states + STATE;

  float* outp = (float*)d_out;
  float* resp = outp + (size_t)TT * DIMC;

  ln_kernel<<<TT, 256, 0, stream>>>(x, pts, nseq, lnw, lnb, u2, resp);

  for (int d = 0; d < 2; ++d) {
    const float* ud = u2 + (size_t)d * TT * DIMC;
    float*       od = o  + (size_t)d * TT * DIMC;
    gemm_nt<<<dim3((DPROJ + 127) / 128, TT / 128), 256, 0, stream>>>(
        ud, W_in, zxbd, TT, DPROJ, DIMC, nullptr);
    conv_plain<<<TT, 256, 0, stream>>>(zxbd, pts, nseq, convw, convb, dtb,
                                       xbcd, dtpd);
    intra_d<<<NH * NCH, 256, 0, stream>>>(xbcd, dtpd, pts, nseq, A_log, Dv,
                                          ysd, states, alpha);
    state_pass_d<<<NH, 256, 0, stream>>>(states, alpha, pts, nseq);
    inter_d<<<NH * NCH, 256, 0, stream>>>(xbcd, dtpd, pts, nseq, A_log,
                                          states, ysd);
    gate_plain<<<TT, 256, 0, stream>>>(ysd, zxbd, gnw);
    gemm_nt<<<dim3(DIMC / 128, TT / 128), 256, 0, stream>>>(
        ysd, W_out, od, TT, DIMC, DIN, nullptr);
  }

  cat_kernel<<<TT, 256, 0, stream>>>(o, pts, nseq, acat);
  gemm_nt<<<dim3(DIMC / 128, TT / 128), 256, 0, stream>>>(
      acat, W_proj, outp, TT, DIMC, 2 * DIMC, b_proj);
}